// Round 1
// baseline (112.461 us; speedup 1.0000x reference)
//
#include <hip/hip_runtime.h>

// Problem: B=128, V=1024, T=1024, C=1024
#define B_ 128
#define V_ 1024
#define T_ 1024
#define C_ 1024
#define KK 2048  // T_ + V_

// Degree-9 Taylor coefficients of f(s) = exp(tanh(s)).
constexpr float C9v[10] = {1.0f,          1.0f,          0.5f,
                           -0.166666667f, -0.291666667f, -0.025f,
                           0.134722222f,  0.054563493f,  -0.051165675f,
                           -0.041377307f};
// Binomial coefficients C(j,p), j<=9
constexpr float BN[10][10] = {
    {1, 0, 0, 0, 0, 0, 0, 0, 0, 0},
    {1, 1, 0, 0, 0, 0, 0, 0, 0, 0},
    {1, 2, 1, 0, 0, 0, 0, 0, 0, 0},
    {1, 3, 3, 1, 0, 0, 0, 0, 0, 0},
    {1, 4, 6, 4, 1, 0, 0, 0, 0, 0},
    {1, 5, 10, 10, 5, 1, 0, 0, 0, 0},
    {1, 6, 15, 20, 15, 6, 1, 0, 0, 0},
    {1, 7, 21, 35, 35, 21, 7, 1, 0, 0},
    {1, 8, 28, 56, 70, 56, 28, 8, 1, 0},
    {1, 9, 36, 84, 126, 126, 84, 36, 9, 1}};
constexpr float FACT[10] = {1.f, 1.f, 2.f, 6.f, 24.f, 120.f,
                            720.f, 5040.f, 40320.f, 362880.f};
constexpr float IFC[10] = {1.f, 1.f, 0.5f, 1.f / 6.f, 1.f / 24.f,
                           1.f / 120.f, 1.f / 720.f, 1.f / 5040.f,
                           1.f / 40320.f, 1.f / 362880.f};

// Fused moment kernel: one block per b (128 blocks x 512 threads, 2 waves/SIMD).
// Block-uniform moment tables M[66], N[55] live in SGPRs (readfirstlane) so the
// per-lane VGPR peak stays under the 256-reg cap for 8-wave blocks.
//  P0: M_{p,q} = sum_t w_t^p x_t^q            (p+q <= 10, 66 moments)
//  P1: per v: dh_i = i! * gamma-shifted coeffs; h = dh_i * (a^p/p!) * (b^q/q!)
//      (== d_i*C(i,p)*a^p*b^q); T1 = denom, T2 = sum e*x;
//      St[b][1024+v] = T2/T1 (text_score); vod = alpha/T1
//  P2: N_{p,q} = sum_v h * vod                 (p+q <= 9, 55 moments)
//  P3: per t: St[b][t] = sum_p w^p (sum_q x^q N_{p,q})   (visual_score)
__global__ __launch_bounds__(512, 2) void kf_moments(
    const float* __restrict__ visual, const float* __restrict__ text,
    const float* __restrict__ w_vis, const float* __restrict__ w_text,
    const float* __restrict__ bias, float* __restrict__ St) {
  const int b = blockIdx.x;
  const int tid = threadIdx.x;
  const int lane = tid & 63, wave = tid >> 6;
  __shared__ float Rw[8][66];
  __shared__ float fin[66];

  // ---------- P0: t-moments ----------
  float mac[66];
#pragma unroll
  for (int r = 0; r < 66; ++r) mac[r] = 0.f;
#pragma unroll
  for (int j = 0; j < 2; ++j) {
    const int t = tid + 512 * j;
    const float w = w_vis[t];
    const float x = text[b * T_ + t];
    float wp[11], xq[11];
    wp[0] = 1.f;
    xq[0] = 1.f;
#pragma unroll
    for (int k = 1; k <= 10; ++k) {
      wp[k] = wp[k - 1] * w;
      xq[k] = xq[k - 1] * x;
    }
#pragma unroll
    for (int i = 0; i <= 10; ++i)
#pragma unroll
      for (int p = 0; p <= i; ++p)
        mac[i * (i + 1) / 2 + p] =
            fmaf(wp[p], xq[i - p], mac[i * (i + 1) / 2 + p]);
  }
#pragma unroll
  for (int m = 1; m <= 32; m <<= 1)
#pragma unroll
    for (int r = 0; r < 66; ++r) mac[r] += __shfl_xor(mac[r], m, 64);
  if (lane == 0) {
#pragma unroll
    for (int r = 0; r < 66; ++r) Rw[wave][r] = mac[r];
  }
  __syncthreads();
  if (tid < 66)
    fin[tid] = ((Rw[0][tid] + Rw[1][tid]) + (Rw[2][tid] + Rw[3][tid])) +
               ((Rw[4][tid] + Rw[5][tid]) + (Rw[6][tid] + Rw[7][tid]));
  __syncthreads();
  int Ms[66];  // block-uniform -> SGPRs
#pragma unroll
  for (int r = 0; r < 66; ++r)
    Ms[r] = __builtin_amdgcn_readfirstlane(__float_as_int(fin[r]));

  // ---------- P1 + P2: per-v eval and v-moments ----------
  float nac[55];
#pragma unroll
  for (int r = 0; r < 55; ++r) nac[r] = 0.f;
#pragma unroll
  for (int j = 0; j < 2; ++j) {
    const int v = tid + 512 * j;
    const float al = visual[b * V_ + v];
    const float be = w_text[v];
    const float ga = bias[v];
    float Ah[10], Bh[10];  // a^p/p!, b^q/q!
    Ah[0] = 1.f;
    Bh[0] = 1.f;
    float aw = 1.f, bw = 1.f;
#pragma unroll
    for (int k = 1; k <= 9; ++k) {
      aw *= al;
      Ah[k] = aw * IFC[k];
      bw *= be;
      Bh[k] = bw * IFC[k];
    }
    // dh_i = i! * d_i = i! * sum_k c_{i+k} C(i+k,i) ga^k   (Horner,
    // constants fold at compile time; compiler emits v_fmaak literals)
    float dh[10];
#pragma unroll
    for (int i = 0; i < 10; ++i) {
      float a = 0.f;
#pragma unroll
      for (int jj = 9; jj >= i; --jj)
        a = fmaf(a, ga, C9v[jj] * BN[jj][i] * FACT[i]);
      dh[i] = a;
    }
    float h[55];
    float T1 = 0.f, T2 = 0.f;
#pragma unroll
    for (int i = 0; i <= 9; ++i)
#pragma unroll
      for (int p = 0; p <= i; ++p) {
        const int ix = i * (i + 1) / 2 + p;
        const int ix2 = (i + 1) * (i + 2) / 2 + p;  // (p, q+1)
        const float hh = dh[i] * Ah[p] * Bh[i - p];
        h[ix] = hh;
        T1 = fmaf(hh, __int_as_float(Ms[ix]), T1);
        T2 = fmaf(hh, __int_as_float(Ms[ix2]), T2);
      }
    const float rd = 1.0f / T1;
    St[b * KK + T_ + v] = T2 * rd;  // text_score
    const float vod = al * rd;
#pragma unroll
    for (int r = 0; r < 55; ++r) nac[r] = fmaf(h[r], vod, nac[r]);
  }
#pragma unroll
  for (int m = 1; m <= 32; m <<= 1)
#pragma unroll
    for (int r = 0; r < 55; ++r) nac[r] += __shfl_xor(nac[r], m, 64);
  if (lane == 0) {
#pragma unroll
    for (int r = 0; r < 55; ++r) Rw[wave][r] = nac[r];
  }
  __syncthreads();
  if (tid < 55)
    fin[tid] = ((Rw[0][tid] + Rw[1][tid]) + (Rw[2][tid] + Rw[3][tid])) +
               ((Rw[4][tid] + Rw[5][tid]) + (Rw[6][tid] + Rw[7][tid]));
  __syncthreads();
  int Ns[55];  // block-uniform -> SGPRs
#pragma unroll
  for (int r = 0; r < 55; ++r)
    Ns[r] = __builtin_amdgcn_readfirstlane(__float_as_int(fin[r]));

  // ---------- P3: per-t eval ----------
#pragma unroll
  for (int j = 0; j < 2; ++j) {
    const int t = tid + 512 * j;
    const float w = w_vis[t];
    const float x = text[b * T_ + t];
    float wp[10], xq[10];
    wp[0] = 1.f;
    xq[0] = 1.f;
#pragma unroll
    for (int k = 1; k <= 9; ++k) {
      wp[k] = wp[k - 1] * w;
      xq[k] = xq[k - 1] * x;
    }
    float vs = 0.f;
#pragma unroll
    for (int p = 0; p <= 9; ++p) {
      float s = 0.f;
#pragma unroll
      for (int q = 0; q <= 9 - p; ++q)
        s = fmaf(xq[q], __int_as_float(Ns[(p + q) * (p + q + 1) / 2 + p]), s);
      vs = fmaf(wp[p], s, vs);
    }
    St[b * KK + t] = vs;  // visual_score
  }
}

// K3: split-K fp32 GEMM, no atomics. part[z][b][c] = sum_{k in slab z}
// St[b][k] * Wcat[c][k]. Tile 32b x 64c, slab K=256, micro 2x4.
// Grid (16, 4, 8) = 512 blocks -> 2 blocks/CU.
#define KC 64
__global__ __launch_bounds__(256, 2) void k3_gemm(
    const float* __restrict__ St, const float* __restrict__ W_fv,
    const float* __restrict__ W_ft, float* __restrict__ part) {
  __shared__ float Ss[KC][36];  // [k][b]
  __shared__ float Ws[KC][68];  // [k][c]
  const int cb = blockIdx.x * 64;
  const int bb = blockIdx.y * 32;
  const int ks = blockIdx.z * 256;
  const float* __restrict__ W = (ks < T_) ? (W_fv + ks) : (W_ft + (ks - T_));
  const int tid = threadIdx.x;
  const int kq4 = tid & 15, br = tid >> 4;  // Ss staging
  const int cr = tid >> 2, kq = tid & 3;    // Ws staging
  const int mb = tid & 15, mc = tid >> 4;   // compute micro-tile
  float acc[2][4] = {};
  for (int kc0 = 0; kc0 < 256; kc0 += KC) {
#pragma unroll
    for (int j = 0; j < 2; ++j) {
      const int row = br + 16 * j;
      float4 g = *(const float4*)&St[(bb + row) * KK + ks + kc0 + 4 * kq4];
      Ss[4 * kq4 + 0][row] = g.x;
      Ss[4 * kq4 + 1][row] = g.y;
      Ss[4 * kq4 + 2][row] = g.z;
      Ss[4 * kq4 + 3][row] = g.w;
    }
#pragma unroll
    for (int j = 0; j < 4; ++j) {
      const int k0 = 16 * j + 4 * kq;
      float4 g = *(const float4*)&W[(cb + cr) * 1024 + kc0 + k0];
      Ws[k0 + 0][cr] = g.x;
      Ws[k0 + 1][cr] = g.y;
      Ws[k0 + 2][cr] = g.z;
      Ws[k0 + 3][cr] = g.w;
    }
    __syncthreads();
#pragma unroll
    for (int k = 0; k < KC; ++k) {
      const float2 s2 = *(const float2*)&Ss[k][2 * mb];
      const float4 w4 = *(const float4*)&Ws[k][4 * mc];
      acc[0][0] = fmaf(s2.x, w4.x, acc[0][0]);
      acc[0][1] = fmaf(s2.x, w4.y, acc[0][1]);
      acc[0][2] = fmaf(s2.x, w4.z, acc[0][2]);
      acc[0][3] = fmaf(s2.x, w4.w, acc[0][3]);
      acc[1][0] = fmaf(s2.y, w4.x, acc[1][0]);
      acc[1][1] = fmaf(s2.y, w4.y, acc[1][1]);
      acc[1][2] = fmaf(s2.y, w4.z, acc[1][2]);
      acc[1][3] = fmaf(s2.y, w4.w, acc[1][3]);
    }
    __syncthreads();
  }
  float* __restrict__ P = part + (size_t)blockIdx.z * (B_ * C_);
#pragma unroll
  for (int i = 0; i < 2; ++i) {
    float4 o = make_float4(acc[i][0], acc[i][1], acc[i][2], acc[i][3]);
    *(float4*)&P[(bb + 2 * mb + i) * C_ + cb + 4 * mc] = o;
  }
}

// K4: out[i] = relu(sum_z part[z][i] + b_fv[c] + b_ft[c]), float4-wide.
__global__ __launch_bounds__(256) void k4_reduce_biasrelu(
    const float* __restrict__ part, const float* __restrict__ b_fv,
    const float* __restrict__ b_ft, float* __restrict__ out) {
  const int i4 = (blockIdx.x * 256 + threadIdx.x) * 4;
  float4 s = *(const float4*)&part[i4];
#pragma unroll
  for (int z = 1; z < 8; ++z) {
    float4 p = *(const float4*)&part[(size_t)z * (B_ * C_) + i4];
    s.x += p.x;
    s.y += p.y;
    s.z += p.z;
    s.w += p.w;
  }
  const int c = i4 & (C_ - 1);
  float4 bf = *(const float4*)&b_fv[c];
  float4 bt = *(const float4*)&b_ft[c];
  float4 o;
  o.x = fmaxf(s.x + bf.x + bt.x, 0.f);
  o.y = fmaxf(s.y + bf.y + bt.y, 0.f);
  o.z = fmaxf(s.z + bf.z + bt.z, 0.f);
  o.w = fmaxf(s.w + bf.w + bt.w, 0.f);
  *(float4*)&out[i4] = o;
}

extern "C" void kernel_launch(void* const* d_in, const int* in_sizes, int n_in,
                              void* d_out, int out_size, void* d_ws, size_t ws_size,
                              hipStream_t stream) {
  const float* visual = (const float*)d_in[0];  // [B,V]
  const float* text   = (const float*)d_in[1];  // [B,T]
  const float* w_vis  = (const float*)d_in[2];  // [T]
  const float* w_text = (const float*)d_in[3];  // [V]
  const float* bias   = (const float*)d_in[4];  // [V]
  const float* W_fv   = (const float*)d_in[5];  // [C,T]
  const float* b_fv   = (const float*)d_in[6];  // [C]
  const float* W_ft   = (const float*)d_in[7];  // [C,V]
  const float* b_ft   = (const float*)d_in[8];  // [C]
  float* out = (float*)d_out;                   // [B,C]

  // ws layout (floats): St[B][2048] | part[8][B*C]   (~5.2 MB)
  float* St = (float*)d_ws;
  float* part = St + (size_t)B_ * KK;

  kf_moments<<<dim3(B_), dim3(512), 0, stream>>>(visual, text, w_vis, w_text,
                                                 bias, St);
  k3_gemm<<<dim3(16, 4, 8), dim3(256), 0, stream>>>(St, W_fv, W_ft, part);
  k4_reduce_biasrelu<<<dim3(B_ * C_ / 1024), dim3(256), 0, stream>>>(
      part, b_fv, b_ft, out);
}